// Round 14
// baseline (473.761 us; speedup 1.0000x reference)
//
#include <hip/hip_runtime.h>
#include <stdint.h>
#include <stddef.h>

#define Bsz   2
#define Ssz   2048
#define HIDsz 4096
#define Hsz   32
#define KVsz  8
#define Dsz   128
#define NQKV  6144                     // (H+2KV)*D
// Q scale = 1/sqrt(128) * log2(e): softmax computed base-2 (exp2 is the HW op)
#define QSCALE 0.12752057463f
#define L2_1E4_64 0.20762050595f       // log2(10000)/64

typedef __bf16 bf16x8 __attribute__((ext_vector_type(8)));
typedef __bf16 bf16x2 __attribute__((ext_vector_type(2)));
typedef float  f32x4  __attribute__((ext_vector_type(4)));
typedef float  f32x16 __attribute__((ext_vector_type(16)));
typedef unsigned short u16;
typedef u16 u16x4 __attribute__((ext_vector_type(4)));
typedef u16 u16x8 __attribute__((ext_vector_type(8)));
typedef uint32_t u32x4 __attribute__((ext_vector_type(4)));

__device__ __forceinline__ u16 f2bf(float f) {
  uint32_t u = __builtin_bit_cast(uint32_t, f);
  u = (u + 0x7FFFu + ((u >> 16) & 1u)) >> 16;   // RNE
  return (u16)u;
}
__device__ __forceinline__ float bf2f(u16 h) {
  return __builtin_bit_cast(float, (uint32_t)h << 16);
}
// pair pack via compiler (emits v_cvt_pk_bf16_f32)
__device__ __forceinline__ uint32_t packc(float lo, float hi_) {
  bf16x2 t;
  t[0] = (__bf16)lo; t[1] = (__bf16)hi_;
  return __builtin_bit_cast(uint32_t, t);
}

// global -> LDS async copy, 16B per lane; LDS dest = wave-uniform base + lane*16
#define GLDS(gp, lp) __builtin_amdgcn_global_load_lds( \
    (__attribute__((address_space(1))) void*)(void*)(gp), \
    (__attribute__((address_space(3))) void*)(lp), 16, 0, 0)

// ---------------- fused fp32->bf16 conversion (one launch, 3 tensors) -------
#define N4_HS  ((Bsz * Ssz * HIDsz) / 4)
#define N4_WQ  ((NQKV * HIDsz) / 4)
#define N4_WO  ((HIDsz * HIDsz) / 4)
__global__ __launch_bounds__(256) void k_cvt3(const float* __restrict__ hs,
                                              const float* __restrict__ wqkv,
                                              const float* __restrict__ wo,
                                              u16* __restrict__ xbf,
                                              u16* __restrict__ wqbf,
                                              u16* __restrict__ wobf) {
  int i = blockIdx.x * 256 + threadIdx.x;
  const float* src; u16* dst; int off;
  if (i < N4_HS)                   { src = hs;   dst = xbf;  off = i; }
  else if (i < N4_HS + N4_WQ)      { src = wqkv; dst = wqbf; off = i - N4_HS; }
  else if (i < N4_HS + N4_WQ + N4_WO) { src = wo; dst = wobf; off = i - N4_HS - N4_WQ; }
  else return;
  float4 v = ((const float4*)src)[off];
  u16x4 o;
  o.x = f2bf(v.x); o.y = f2bf(v.y); o.z = f2bf(v.z); o.w = f2bf(v.w);
  ((u16x4*)dst)[off] = o;
}

// ============ 256x256 8-phase GEMM: C[M][N] = A[M][K] * B[N][K]^T ============
// MODE 0: plain fp32 C-write (o_proj), grid M/256 x N/256, stride N.
// MODE 1: Q-region of qkv-proj (bn 0..15, 256 blocks): fused RoPE-Q epilogue.
// MODE 2: K/V-region K-split partials: 128 tiles (bn 16..23) x 2 K-halves.

#define BARX do { asm volatile("" ::: "memory"); __builtin_amdgcn_s_barrier(); \
                  asm volatile("" ::: "memory"); } while (0)
#define VM6  asm volatile("s_waitcnt vmcnt(6)" ::: "memory")
#define VM0  asm volatile("s_waitcnt vmcnt(0)" ::: "memory")

#define LOADA4(P_, Q_, F_) do {                                               \
    afr[F_][0] = LDA(P_, Q_, 0, 0); afr[F_][1] = LDA(P_, Q_, 0, 1);           \
    afr[F_][2] = LDA(P_, Q_, 1, 0); afr[F_][3] = LDA(P_, Q_, 1, 1);           \
  } while (0)

#define LOADB8(P_) do {                                                       \
    _Pragma("unroll") for (int nf = 0; nf < 4; ++nf) {                        \
      bfr[nf][0] = LDB(P_, nf, 0); bfr[nf][1] = LDB(P_, nf, 1); }             \
  } while (0)

#define MMA16(Q_, F_) do {                                                    \
    __builtin_amdgcn_s_setprio(1);                                            \
    _Pragma("unroll") for (int nf = 0; nf < 4; ++nf) {                        \
      acc[(Q_)*2][nf]   = __builtin_amdgcn_mfma_f32_16x16x32_bf16(afr[F_][0], bfr[nf][0], acc[(Q_)*2][nf],   0,0,0); \
      acc[(Q_)*2+1][nf] = __builtin_amdgcn_mfma_f32_16x16x32_bf16(afr[F_][2], bfr[nf][0], acc[(Q_)*2+1][nf], 0,0,0); \
    }                                                                         \
    _Pragma("unroll") for (int nf = 0; nf < 4; ++nf) {                        \
      acc[(Q_)*2][nf]   = __builtin_amdgcn_mfma_f32_16x16x32_bf16(afr[F_][1], bfr[nf][1], acc[(Q_)*2][nf],   0,0,0); \
      acc[(Q_)*2+1][nf] = __builtin_amdgcn_mfma_f32_16x16x32_bf16(afr[F_][3], bfr[nf][1], acc[(Q_)*2+1][nf], 0,0,0); \
    }                                                                         \
    __builtin_amdgcn_s_setprio(0);                                            \
  } while (0)

#define TLS 258                         // MODE1 epilogue LDS tile stride (u16)

template <int MODE>
__global__ __launch_bounds__(512, 1) void k_gemm256(const u16* __restrict__ A,
                                                    const u16* __restrict__ Bm,
                                                    float* __restrict__ Cv,
                                                    const int* __restrict__ pos,
                                                    u16* __restrict__ Qr,
                                                    int M, int N, int K_ld,
                                                    int K_len) {
  constexpr int LDS_BYTES = (MODE == 1) ? (256 * TLS * 2) : (4 * 256 * 64 * 2);
  __shared__ __align__(16) char LDSBUF[LDS_BYTES];
  u16* SA0 = (u16*)LDSBUF;                        // SA[2][256*64]
  u16* SB0 = (u16*)(LDSBUF + 65536);              // SB[2][256*64]
  const int tid = threadIdx.x;
  const int w = tid >> 6, lane = tid & 63;
  const int g = lane >> 4, t = lane & 15;
  const int wr = w >> 2, wc = w & 3;
  const int cpx = gridDim.x >> 3;                 // grid %8 == 0 (always 256)
  const int swz = (blockIdx.x & 7) * cpx + (blockIdx.x >> 3);

  int bm, bn;
  const u16 *Au = A, *Bu = Bm;
  float* Cu = Cv;
  if constexpr (MODE == 2) {
    const int t2 = swz & 127, h2 = swz >> 7;
    bm = t2 & 15; bn = 16 + (t2 >> 4);
    Au = A + h2 * 2048; Bu = Bm + h2 * 2048;
    Cu = Cv + (size_t)h2 * 4096 * 2048;
  } else {
    const int MBt = M >> 8;
    bm = swz % MBt; bn = swz / MBt;               // column-major tile order
  }
  const int m0 = bm << 8, n0 = bn << 8;

  const char* Ab = (const char*)Au;
  const char* Bb = (const char*)Bu;
  const size_t rowK = (size_t)K_ld * 2;           // bytes per input row
  const int srcx = ((lane & 7) ^ (lane >> 3)) << 4;  // pre-swizzled src col
  const int l3 = lane >> 3;
  const int tx = (t & 7) << 4;                    // read-side XOR (bytes)

  auto SToff = [&](int h, int j) -> int {
    int ii = w * 2 + j;
    return (ii < 8) ? (h * 64 + ii * 8) : (128 + h * 64 + (ii - 8) * 8);
  };
  auto STAGE_A = [&](int p, int T, int h) {
#pragma unroll
    for (int j = 0; j < 2; ++j) {
      int rb = SToff(h, j);
      GLDS(Ab + (size_t)(m0 + rb + l3) * rowK + (size_t)T * 128 + srcx,
           &SA0[p * 16384 + rb * 64]);
    }
  };
  auto STAGE_B = [&](int p, int T, int h) {
#pragma unroll
    for (int j = 0; j < 2; ++j) {
      int rb = SToff(h, j);
      GLDS(Bb + (size_t)(n0 + rb + l3) * rowK + (size_t)T * 128 + srcx,
           &SB0[p * 16384 + rb * 64]);
    }
  };
  auto LDA = [&](int p, int q, int fr, int kk) -> bf16x8 {
    int ar = wr * 128 + q * 32 + fr * 16 + t;
    const char* ptr = (const char*)&SA0[p * 16384] + ar * 128 + ((kk * 64 + 16 * g) ^ tx);
    return __builtin_bit_cast(bf16x8, *(const u16x8*)ptr);
  };
  auto LDB = [&](int p, int nf, int kk) -> bf16x8 {
    int br = wc * 64 + nf * 16 + t;
    const char* ptr = (const char*)&SB0[p * 16384] + br * 128 + ((kk * 64 + 16 * g) ^ tx);
    return __builtin_bit_cast(bf16x8, *(const u16x8*)ptr);
  };

  f32x4 acc[8][4];
#pragma unroll
  for (int i = 0; i < 8; ++i)
#pragma unroll
    for (int j = 0; j < 4; ++j) acc[i][j] = (f32x4){0.f, 0.f, 0.f, 0.f};
  bf16x8 bfr[4][2];
  bf16x8 afr[2][4];

  // prologue: T0 complete (8 loads) + T1.{A0,B0,B1} (6 loads)
  STAGE_A(0, 0, 0); STAGE_B(0, 0, 0); STAGE_A(0, 0, 1); STAGE_B(0, 0, 1);
  STAGE_A(1, 1, 0); STAGE_B(1, 1, 0); STAGE_B(1, 1, 1);
  VM6;                                            // T0 landed
  __builtin_amdgcn_s_barrier();

  const int NI = (K_len >> 7) - 1;
  for (int i = 0; i < NI; ++i) {
    const int T1 = 2 * i + 1, T2 = 2 * i + 2, T3 = 2 * i + 3;
    LOADB8(0); LOADA4(0, 0, 0);
    STAGE_A(1, T1, 1); LOADA4(0, 1, 1); MMA16(0, 0); BARX;
    STAGE_B(0, T2, 0); LOADA4(0, 2, 0); MMA16(1, 1); BARX;
    STAGE_B(0, T2, 1); LOADA4(0, 3, 1); MMA16(2, 0); BARX;
    STAGE_A(0, T2, 0); MMA16(3, 1); VM6; BARX;
    LOADB8(1); LOADA4(1, 0, 0);
    STAGE_A(0, T2, 1); LOADA4(1, 1, 1); MMA16(0, 0); BARX;
    STAGE_B(1, T3, 0); LOADA4(1, 2, 0); MMA16(1, 1); BARX;
    STAGE_A(1, T3, 0); LOADA4(1, 3, 1); MMA16(2, 0); BARX;
    STAGE_B(1, T3, 1); MMA16(3, 1); VM6; BARX;
  }
  {                                               // peeled final iteration
    const int TL_ = (K_len >> 6) - 1;
    LOADB8(0); LOADA4(0, 0, 0);
    STAGE_A(1, TL_, 1); LOADA4(0, 1, 1); MMA16(0, 0); BARX;
    LOADA4(0, 2, 0); MMA16(1, 1); BARX;
    LOADA4(0, 3, 1); MMA16(2, 0); BARX;
    MMA16(3, 1); VM0; BARX;
    LOADB8(1); LOADA4(1, 0, 0);
    LOADA4(1, 1, 1); MMA16(0, 0); BARX;
    LOADA4(1, 2, 0); MMA16(1, 1); BARX;
    LOADA4(1, 3, 1); MMA16(2, 0); BARX;
    MMA16(3, 1);
  }

  if constexpr (MODE == 0 || MODE == 2) {
    // fp32 C-write (row = 4*(lane>>4)+reg, col = lane&15)
    const int cstride = (MODE == 0) ? N : 2048;
    const int cbase   = (MODE == 0) ? n0 : (n0 - 4096);
#pragma unroll
    for (int fi = 0; fi < 8; ++fi)
#pragma unroll
      for (int nf = 0; nf < 4; ++nf)
#pragma unroll
        for (int r = 0; r < 4; ++r) {
          int row = m0 + wr * 128 + fi * 16 + 4 * g + r;
          int col = cbase + wc * 64 + nf * 16 + t;
          Cu[(size_t)row * cstride + col] = acc[fi][nf][r];
        }
  } else {
    // MODE 1: fused RoPE-Q epilogue (n0 < 4096 always)
    u16* TL = (u16*)LDSBUF;                       // [256][TLS]
    __syncthreads();                              // all LDS reads of K-loop done
#pragma unroll
    for (int fi = 0; fi < 8; ++fi)
#pragma unroll
      for (int nf = 0; nf < 4; ++nf)
#pragma unroll
        for (int r = 0; r < 4; ++r)
          TL[(wr * 128 + fi * 16 + 4 * g + r) * TLS + wc * 64 + nf * 16 + t] =
              f2bf(acc[fi][nf][r]);
    __syncthreads();

    const int j = lane;                           // 0..63 = pair index
    const float ifr = exp2f(-(float)j * L2_1E4_64);
#pragma unroll 1
    for (int it = 0; it < 64; ++it) {
      int combo = w * 64 + it;                    // 0..511
      int row = combo & 255;
      int hh = combo >> 8;                        // 0/1: head within tile
      int tok = m0 + row;
      int b = tok >> 11, s = tok & (Ssz - 1);
      float x1 = bf2f(TL[row * TLS + hh * 128 + j]);
      float x2 = bf2f(TL[row * TLS + hh * 128 + 64 + j]);
      float p = (float)pos[tok];
      float ang = p * ifr;
      float sn, cs;
      __sincosf(ang, &sn, &cs);
      float o1 = (x1 * cs - x2 * sn) * QSCALE;
      float o2 = (x2 * cs + x1 * sn) * QSCALE;
      int h = (n0 >> 7) + hh;
      u16* o = Qr + ((size_t)(b * Hsz + h) * Ssz + s) * Dsz;
      o[j] = f2bf(o1); o[j + 64] = f2bf(o2);
    }
  }
}

// --------- K-region: sum K-split partials + RoPE -> Kr[b][kvh][s][d] --------
__global__ __launch_bounds__(256) void k_ropeK2(const float* __restrict__ Cp,
                                                const int* __restrict__ pos,
                                                u16* __restrict__ Kr) {
  int idx = blockIdx.x * 256 + threadIdx.x;       // B*S*KV*64
  if (idx >= Bsz * Ssz * KVsz * 64) return;
  const size_t OFF2 = (size_t)4096 * 2048;
  int j = idx & 63;
  int kvh = (idx >> 6) & 7;
  int bs = idx >> 9;                              // 0..4095
  size_t p0 = (size_t)bs * 2048 + kvh * 128 + j;
  float x1 = Cp[p0] + Cp[p0 + OFF2];
  float x2 = Cp[p0 + 64] + Cp[p0 + 64 + OFF2];
  float p = (float)pos[bs];
  float ang = p * exp2f(-(float)j * L2_1E4_64);
  float sn, cs;
  __sincosf(ang, &sn, &cs);
  int b = bs >> 11, sidx = bs & (Ssz - 1);
  u16* o = Kr + ((size_t)(b * KVsz + kvh) * Ssz + sidx) * Dsz;
  o[j] = f2bf(x1 * cs - x2 * sn);
  o[j + 64] = f2bf(x2 * cs + x1 * sn);
}

// --------- V-region: sum partials + LDS transpose -> Vt[bk][d][s] -----------
__global__ __launch_bounds__(256) void k_vtrans2(const float* __restrict__ Cp,
                                                 u16* __restrict__ Vt) {
  __shared__ __align__(16) u16 Tl[64 * 72];
  const int tid = threadIdx.x;
  const int bk = blockIdx.y;                      // b*KV + kvh
  const int s0 = (blockIdx.x >> 1) * 64;
  const int d0 = (blockIdx.x & 1) * 64;
  const int b = bk >> 3, kvh = bk & 7;
  const size_t OFF2 = (size_t)4096 * 2048;
  const size_t base = (size_t)(b * Ssz + s0) * 2048 + 1024 + kvh * 128 + d0;
#pragma unroll
  for (int p = 0; p < 2; ++p) {
    int cid = p * 256 + tid;
    int r = cid >> 3, co = cid & 7;
    int chunk = co ^ ((r >> 3) & 7);
    const float* s1 = Cp + base + (size_t)r * 2048 + co * 8;
    u16x8 v;
#pragma unroll
    for (int e = 0; e < 8; ++e) v[e] = f2bf(s1[e] + s1[OFF2 + e]);
    *(u16x8*)((char*)Tl + r * 144 + chunk * 16) = v;
  }
  __syncthreads();
#pragma unroll
  for (int p = 0; p < 2; ++p) {
    int cid = p * 256 + tid;
    int dr = cid >> 3, c = cid & 7;
    u16x8 v;
#pragma unroll
    for (int j = 0; j < 8; ++j) {
      int s = 8 * c + j;
      v[j] = *(const u16*)((char*)Tl + s * 144 + (((dr >> 3) ^ c) * 16) + (dr & 7) * 2);
    }
    *(u16x8*)(Vt + ((size_t)bk * Dsz + d0 + dr) * Ssz + s0 + 8 * c) = v;
  }
}

// ---------------- flash attention: 8-wave swapped-QK^T 32x32 ----------------
// r14: T4 counted-vmcnt pipeline — 3 KV buffers (96KB), STAGE(kt+2) issued
// before compute(kt), per-tile barrier = s_waitcnt vmcnt(4) (wait ONLY tile
// kt+1's 4 loads; kt+2's stay in flight) + raw s_barrier. Never a full vmem
// drain in the loop (r12/r13: __syncthreads drained the just-issued prefetch
// = full L2 latency exposed every tile). 512 thr / 8 waves / 1 block/CU;
// r12 triangle fold (bx 0..3, pairs (7-bx, bx), 36 tiles uniform).
// Buffer ledger: buf kt%3 overwritten by STAGE at tile kt-2's compute-start,
// which is AFTER tile kt-3's end-barrier; its last read was tile kt-3. Safe.
__global__ __launch_bounds__(512, 1) void k_attn(const u16* __restrict__ Qr,
                                                 const u16* __restrict__ Kr,
                                                 const u16* __restrict__ Vt,
                                                 u16* __restrict__ AO) {
  __shared__ __align__(16) u16 Kl[3][64 * 128];  // [k][d] swizzled, 16KB each
  __shared__ __align__(16) u16 Vl[3][128 * 64];  // [d][k] swizzled, 16KB each
  const int tid = threadIdx.x;                   // 0..511
  const int w = tid >> 6, lane = tid & 63;       // w: 0..7
  const int q = lane & 31, hi = lane >> 5;
  const int bh = blockIdx.y;
  const int b = bh >> 5, h = bh & 31;
  const int kvh = h >> 2;                        // GQA: H/KV = 4
  const int bx = blockIdx.x;                     // 0..3

  // loop-invariant LDS read byte-offsets (statically indexed -> registers)
  const int xq = (q & 7) << 4;
  int koff[8][2], voff[4][4];
#pragma unroll
  for (int ds = 0; ds < 8; ++ds) {
    int c = (ds * 32 + hi * 16) ^ xq;
    koff[ds][0] = q * 256 + c;
    koff[ds][1] = (32 + q) * 256 + c;
  }
#pragma unroll
  for (int ks = 0; ks < 4; ++ks) {
    int c = (ks * 32 + hi * 16) ^ xq;
#pragma unroll
    for (int dt = 0; dt < 4; ++dt)
      voff[ks][dt] = (dt * 32 + q) * 128 + c;
  }

  const char* Kbase = (const char*)(Kr + (size_t)(b * KVsz + kvh) * Ssz * Dsz);
  const char* Vbase = (const char*)(Vt + (size_t)(b * KVsz + kvh) * Dsz * Ssz);

  auto STAGE = [&](int bu, int kt2) {            // 512 thr: 2 K + 2 V GLDS each
    const char* Kb = Kbase + (size_t)kt2 * (64 * 256);
    const char* Vb = Vbase + (size_t)kt2 * 128;   // 64 cols * 2B
#pragma unroll
    for (int j = 0; j < 2; ++j) {
      int flat = j * 512 + tid;
      int row = flat >> 4, colb = ((flat & 15) * 16) ^ ((row & 7) << 4);
      GLDS(Kb + (size_t)row * 256 + colb, (char*)&Kl[bu][0] + flat * 16);
    }
#pragma unroll
    for (int j = 0; j < 2; ++j) {
      int flat = j * 512 + tid;
      int row = flat >> 3, colb = ((flat & 7) * 16) ^ ((row & 7) << 4);
      GLDS(Vb + (size_t)row * (Ssz * 2) + colb, (char*)&Vl[bu][0] + flat * 16);
    }
  };

#pragma unroll 1
  for (int pass = 0; pass < 2; ++pass) {
    const int bxr = pass ? bx : (7 - bx);
    const int q0 = bxr * 256;
    const int qw = q0 + w * 32;
    const int ntiles = 4 * bxr + 4;              // >= 4 always
    const int qg = qw + q;

    const u16* Qb = Qr + ((size_t)bh * Ssz + qw + q) * Dsz + hi * 8;
    bf16x8 qf[8];
#pragma unroll
    for (int ds = 0; ds < 8; ++ds)
      qf[ds] = __builtin_bit_cast(bf16x8, *(const u16x8*)(Qb + ds * 16));

    f32x16 oacc[4];
#pragma unroll
    for (int dt = 0; dt < 4; ++dt)
#pragma unroll
      for (int r = 0; r < 16; ++r) oacc[dt][r] = 0.f;
    float mr = -1e30f, lr = 0.f;

    // prologue: tiles 0 and 1 in flight; wait tile 0 only (vmcnt(4))
    STAGE(0, 0);
    STAGE(1, 1);
    asm volatile("s_waitcnt vmcnt(4)" ::: "memory");
    __builtin_amdgcn_s_barrier();
    asm volatile("" ::: "memory");

    int bc = 0, sc = 2;                          // compute buf / stage buf
#pragma unroll 1
    for (int kt = 0; kt < ntiles; ++kt) {
      if (kt + 2 < ntiles) {                     // issue-early prefetch (T14)
        STAGE(sc, kt + 2);
        sc = (sc == 2) ? 0 : sc + 1;
      }
      const int k0 = kt * 64;
      if (k0 <= qw + 31) {                       // wave participates
        const char* Kb = (const char*)&Kl[bc][0];
        const char* Vb = (const char*)&Vl[bc][0];
        f32x16 pa0, pa1;
#pragma unroll
        for (int r = 0; r < 16; ++r) { pa0[r] = 0.f; pa1[r] = 0.f; }
        __builtin_amdgcn_s_setprio(1);
#pragma unroll
        for (int ds = 0; ds < 8; ++ds) {
          bf16x8 kf0 = __builtin_bit_cast(bf16x8, *(const u16x8*)(Kb + koff[ds][0]));
          pa0 = __builtin_amdgcn_mfma_f32_32x32x16_bf16(kf0, qf[ds], pa0, 0, 0, 0);
          bf16x8 kf1 = __builtin_bit_cast(bf16x8, *(const u16x8*)(Kb + koff[ds][1]));
          pa1 = __builtin_amdgcn_mfma_f32_32x32x16_bf16(kf1, qf[ds], pa1, 0, 0, 0);
        }
        __builtin_amdgcn_s_setprio(0);

        if (k0 + 63 > qw) {                      // causal mask (tail tiles)
#pragma unroll
          for (int reg = 0; reg < 16; ++reg) {
            const int kb = (reg & 3) + 8 * (reg >> 2) + 4 * hi;
            if (k0 + kb > qg)      pa0[reg] = -1e30f;
            if (k0 + 32 + kb > qg) pa1[reg] = -1e30f;
          }
        }
        float tmx[16];
#pragma unroll
        for (int i = 0; i < 16; ++i) tmx[i] = fmaxf(pa0[i], pa1[i]);
#pragma unroll
        for (int s = 8; s > 0; s >>= 1)
#pragma unroll
          for (int i = 0; i < s; ++i) tmx[i] = fmaxf(tmx[i], tmx[i + s]);
        const float mx = fmaxf(tmx[0], __shfl_xor(tmx[0], 32, 64));
        if (!__all(mx <= mr + 4.0f)) {           // T13 defer-max
          const float mnew = fmaxf(mr, mx);
          const float corr = exp2f(mr - mnew);
          lr *= corr;
#pragma unroll
          for (int dt = 0; dt < 4; ++dt)
#pragma unroll
            for (int reg = 0; reg < 16; ++reg) oacc[dt][reg] *= corr;
          mr = mnew;
        }
        float su[16];
#pragma unroll
        for (int reg = 0; reg < 16; ++reg) {
          pa0[reg] = exp2f(pa0[reg] - mr);
          pa1[reg] = exp2f(pa1[reg] - mr);
          su[reg] = pa0[reg] + pa1[reg];
        }
#pragma unroll
        for (int s = 8; s > 0; s >>= 1)
#pragma unroll
          for (int i = 0; i < s; ++i) su[i] += su[i + s];
        lr += su[0] + __shfl_xor(su[0], 32, 64);

        uint32_t W0[4][2], W1[4][2];
#pragma unroll
        for (int r2 = 0; r2 < 4; ++r2)
#pragma unroll
          for (int c = 0; c < 2; ++c) {
            W0[r2][c] = packc(pa0[4 * r2 + 2 * c], pa0[4 * r2 + 2 * c + 1]);
            W1[r2][c] = packc(pa1[4 * r2 + 2 * c], pa1[4 * r2 + 2 * c + 1]);
          }

        __builtin_amdgcn_s_setprio(1);
#pragma unroll
        for (int ks = 0; ks < 4; ++ks) {
          const int T = ks >> 1, r2e = 2 * (ks & 1);
          uint32_t a0 = T ? W1[r2e][0]     : W0[r2e][0];
          uint32_t a1 = T ? W1[r2e][1]     : W0[r2e][1];
          uint32_t b0 = T ? W1[r2e + 1][0] : W0[r2e + 1][0];
          uint32_t b1 = T ? W1[r2e + 1][1] : W0[r2e + 1][1];
          asm("v_permlane32_swap_b32 %0, %1" : "+v"(a0), "+v"(b0));
          asm("v_permlane32_swap_b32 %0, %1" : "+v"(a1), "+v"(b1));
          u32x4 fw; fw[0] = a0; fw[1] = a1; fw[2] = b0; fw[3] = b1;
          bf16x8 pf = __builtin_bit_cast(bf16x8, fw);
#pragma unroll
          for (int dt = 0; dt < 4; ++dt) {
            bf16x8 vf = __builtin_bit_cast(bf16x8, *(const u16x8*)(Vb + voff[ks][dt]));
            oacc[dt] = __builtin_amdgcn_mfma_f32_32x32x16_bf16(vf, pf, oacc[dt], 0, 0, 0);
          }
        }
        __builtin_amdgcn_s_setprio(0);
      }
      // end-of-tile: wait ONLY tile kt+1's stage (counted), keep kt+2 in flight
      if (kt + 1 < ntiles) {
        asm volatile("" ::: "memory");
        if (kt + 2 < ntiles) asm volatile("s_waitcnt vmcnt(4)" ::: "memory");
        else                 asm volatile("s_waitcnt vmcnt(0)" ::: "memory");
        __builtin_amdgcn_s_barrier();
        asm volatile("" ::: "memory");
      }
      bc = (bc == 2) ? 0 : bc + 1;
    }
    __syncthreads();                             // reads done before next pass

    const float inv = 1.f / lr;
    u16* Ob = AO + ((size_t)(b * Ssz) + qw + q) * HIDsz + h * Dsz + hi * 4;
#pragma unroll
    for (int dt = 0; dt < 4; ++dt)
#pragma unroll
      for (int r2 = 0; r2 < 4; ++r2) {
        u16x4 o4;
#pragma unroll
        for (int j = 0; j < 4; ++j) o4[j] = f2bf(oacc[dt][4 * r2 + j] * inv);
        *(u16x4*)(Ob + dt * 32 + r2 * 8) = o4;
      }
  }
}

// ---------------- host ----------------
extern "C" void kernel_launch(void* const* d_in, const int* in_sizes, int n_in,
                              void* d_out, int out_size, void* d_ws, size_t ws_size,
                              hipStream_t stream) {
  (void)in_sizes; (void)n_in; (void)out_size;
  const float* hs   = (const float*)d_in[0];
  const int*   pos  = (const int*)d_in[1];
  const float* Wqkv = (const float*)d_in[2];
  const float* Wo   = (const float*)d_in[3];

  char* ws = (char*)d_ws;
  const size_t SZ_XBF = (size_t)4096 * 4096 * 2;   // also reused for AO
  const size_t SZ_WQ  = (size_t)6144 * 4096 * 2;
  const size_t SZ_WO  = (size_t)4096 * 4096 * 2;
  const size_t SZ_QR  = (size_t)Bsz * Hsz * Ssz * Dsz * 2;
  const size_t SZ_KR  = (size_t)Bsz * KVsz * Ssz * Dsz * 2;
  const size_t SZ_VT  = SZ_KR;

  size_t off = 0;
  u16*   Xbf   = (u16*)(ws + off);  off += SZ_XBF;
  u16*   Wq_bf = (u16*)(ws + off);  off += SZ_WQ;
  u16*   Wo_bf = (u16*)(ws + off);  off += SZ_WO;
  u16*   Qr    = (u16*)(ws + off);  off += SZ_QR;
  u16*   Kr    = (u16*)(ws + off);  off += SZ_KR;
  u16*   Vt    = (u16*)(ws + off);  off += SZ_VT;
  u16*   AO    = Xbf;                               // alias (Xbf dead after gemm1)
  float* Cp    = (float*)d_out;                     // K-split partials: d_out as
                                                    // scratch, fully overwritten
                                                    // by gemm2 afterwards
  if (ws_size < off) return;                        // fail loudly

  // 1. fp32 -> bf16 conversions (single launch)
  k_cvt3<<<(N4_HS + N4_WQ + N4_WO + 255) / 256, 256, 0, stream>>>(
      hs, Wqkv, Wo, Xbf, Wq_bf, Wo_bf);

  // 2a. QKV projection, Q region (256 blocks, 1 clean round) + RoPE-Q -> Qr
  k_gemm256<1><<<256, 512, 0, stream>>>(Xbf, Wq_bf, nullptr, pos, Qr,
                                        Bsz * Ssz, NQKV, HIDsz, HIDsz);

  // 2b. K/V region K-split partials (256 blocks, 1 clean half-round) -> Cp
  k_gemm256<2><<<256, 512, 0, stream>>>(Xbf, Wq_bf, Cp, nullptr, nullptr,
                                        Bsz * Ssz, NQKV, HIDsz, 2048);

  // 2c. sum partials + RoPE-K -> Kr ; sum + transpose -> Vt
  k_ropeK2<<<(Bsz * Ssz * KVsz * 64) / 256, 256, 0, stream>>>(Cp, pos, Kr);
  k_vtrans2<<<dim3(64, Bsz * KVsz), 256, 0, stream>>>(Cp, Vt);

  // 3. causal GQA attention (folded triangle, 3-buffer counted-vmcnt) -> AO
  k_attn<<<dim3(4, Bsz * Hsz), 512, 0, stream>>>(Qr, Kr, Vt, AO);

  // 4. o_proj: [4096,4096] x [4096,4096]^T -> d_out fp32 (overwrites scratch)
  k_gemm256<0><<<256, 512, 0, stream>>>(AO, Wo_bf, (float*)d_out, nullptr,
                                        nullptr, Bsz * Ssz, HIDsz, HIDsz, HIDsz);
}

// Round 15
// 458.607 us; speedup vs baseline: 1.0330x; 1.0330x over previous
//
#include <hip/hip_runtime.h>
#include <stdint.h>
#include <stddef.h>

#define Bsz   2
#define Ssz   2048
#define HIDsz 4096
#define Hsz   32
#define KVsz  8
#define Dsz   128
#define NQKV  6144                     // (H+2KV)*D
// Q scale = 1/sqrt(128) * log2(e): softmax computed base-2 (exp2 is the HW op)
#define QSCALE 0.12752057463f
#define L2_1E4_64 0.20762050595f       // log2(10000)/64

typedef __bf16 bf16x8 __attribute__((ext_vector_type(8)));
typedef __bf16 bf16x2 __attribute__((ext_vector_type(2)));
typedef float  f32x4  __attribute__((ext_vector_type(4)));
typedef float  f32x16 __attribute__((ext_vector_type(16)));
typedef unsigned short u16;
typedef u16 u16x4 __attribute__((ext_vector_type(4)));
typedef u16 u16x8 __attribute__((ext_vector_type(8)));
typedef uint32_t u32x4 __attribute__((ext_vector_type(4)));

__device__ __forceinline__ u16 f2bf(float f) {
  uint32_t u = __builtin_bit_cast(uint32_t, f);
  u = (u + 0x7FFFu + ((u >> 16) & 1u)) >> 16;   // RNE
  return (u16)u;
}
__device__ __forceinline__ float bf2f(u16 h) {
  return __builtin_bit_cast(float, (uint32_t)h << 16);
}
// pair pack via compiler (emits v_cvt_pk_bf16_f32)
__device__ __forceinline__ uint32_t packc(float lo, float hi_) {
  bf16x2 t;
  t[0] = (__bf16)lo; t[1] = (__bf16)hi_;
  return __builtin_bit_cast(uint32_t, t);
}

// global -> LDS async copy, 16B per lane; LDS dest = wave-uniform base + lane*16
#define GLDS(gp, lp) __builtin_amdgcn_global_load_lds( \
    (__attribute__((address_space(1))) void*)(void*)(gp), \
    (__attribute__((address_space(3))) void*)(lp), 16, 0, 0)

// ---------------- fused fp32->bf16 conversion (one launch, 3 tensors) -------
#define N4_HS  ((Bsz * Ssz * HIDsz) / 4)
#define N4_WQ  ((NQKV * HIDsz) / 4)
#define N4_WO  ((HIDsz * HIDsz) / 4)
__global__ __launch_bounds__(256) void k_cvt3(const float* __restrict__ hs,
                                              const float* __restrict__ wqkv,
                                              const float* __restrict__ wo,
                                              u16* __restrict__ xbf,
                                              u16* __restrict__ wqbf,
                                              u16* __restrict__ wobf) {
  int i = blockIdx.x * 256 + threadIdx.x;
  const float* src; u16* dst; int off;
  if (i < N4_HS)                   { src = hs;   dst = xbf;  off = i; }
  else if (i < N4_HS + N4_WQ)      { src = wqkv; dst = wqbf; off = i - N4_HS; }
  else if (i < N4_HS + N4_WQ + N4_WO) { src = wo; dst = wobf; off = i - N4_HS - N4_WQ; }
  else return;
  float4 v = ((const float4*)src)[off];
  u16x4 o;
  o.x = f2bf(v.x); o.y = f2bf(v.y); o.z = f2bf(v.z); o.w = f2bf(v.w);
  ((u16x4*)dst)[off] = o;
}

// ============ 256x256 8-phase GEMM: C[M][N] = A[M][K] * B[N][K]^T ============
// MODE 0: plain fp32 C-write (o_proj), grid M/256 x N/256, stride N.
// MODE 1: Q-region of qkv-proj (bn 0..15, 256 blocks): fused RoPE-Q epilogue.
// MODE 2: K/V-region K-split partials: 128 tiles (bn 16..23) x 2 K-halves.

#define BARX do { asm volatile("" ::: "memory"); __builtin_amdgcn_s_barrier(); \
                  asm volatile("" ::: "memory"); } while (0)
#define VM6  asm volatile("s_waitcnt vmcnt(6)" ::: "memory")
#define VM0  asm volatile("s_waitcnt vmcnt(0)" ::: "memory")

#define LOADA4(P_, Q_, F_) do {                                               \
    afr[F_][0] = LDA(P_, Q_, 0, 0); afr[F_][1] = LDA(P_, Q_, 0, 1);           \
    afr[F_][2] = LDA(P_, Q_, 1, 0); afr[F_][3] = LDA(P_, Q_, 1, 1);           \
  } while (0)

#define LOADB8(P_) do {                                                       \
    _Pragma("unroll") for (int nf = 0; nf < 4; ++nf) {                        \
      bfr[nf][0] = LDB(P_, nf, 0); bfr[nf][1] = LDB(P_, nf, 1); }             \
  } while (0)

#define MMA16(Q_, F_) do {                                                    \
    __builtin_amdgcn_s_setprio(1);                                            \
    _Pragma("unroll") for (int nf = 0; nf < 4; ++nf) {                        \
      acc[(Q_)*2][nf]   = __builtin_amdgcn_mfma_f32_16x16x32_bf16(afr[F_][0], bfr[nf][0], acc[(Q_)*2][nf],   0,0,0); \
      acc[(Q_)*2+1][nf] = __builtin_amdgcn_mfma_f32_16x16x32_bf16(afr[F_][2], bfr[nf][0], acc[(Q_)*2+1][nf], 0,0,0); \
    }                                                                         \
    _Pragma("unroll") for (int nf = 0; nf < 4; ++nf) {                        \
      acc[(Q_)*2][nf]   = __builtin_amdgcn_mfma_f32_16x16x32_bf16(afr[F_][1], bfr[nf][1], acc[(Q_)*2][nf],   0,0,0); \
      acc[(Q_)*2+1][nf] = __builtin_amdgcn_mfma_f32_16x16x32_bf16(afr[F_][3], bfr[nf][1], acc[(Q_)*2+1][nf], 0,0,0); \
    }                                                                         \
    __builtin_amdgcn_s_setprio(0);                                            \
  } while (0)

#define TLS 258                         // MODE1 epilogue LDS tile stride (u16)

template <int MODE>
__global__ __launch_bounds__(512, 1) void k_gemm256(const u16* __restrict__ A,
                                                    const u16* __restrict__ Bm,
                                                    float* __restrict__ Cv,
                                                    const int* __restrict__ pos,
                                                    u16* __restrict__ Qr,
                                                    int M, int N, int K_ld,
                                                    int K_len) {
  constexpr int LDS_BYTES = (MODE == 1) ? (256 * TLS * 2) : (4 * 256 * 64 * 2);
  __shared__ __align__(16) char LDSBUF[LDS_BYTES];
  u16* SA0 = (u16*)LDSBUF;                        // SA[2][256*64]
  u16* SB0 = (u16*)(LDSBUF + 65536);              // SB[2][256*64]
  const int tid = threadIdx.x;
  const int w = tid >> 6, lane = tid & 63;
  const int g = lane >> 4, t = lane & 15;
  const int wr = w >> 2, wc = w & 3;
  const int cpx = gridDim.x >> 3;                 // grid %8 == 0 (always 256)
  const int swz = (blockIdx.x & 7) * cpx + (blockIdx.x >> 3);

  int bm, bn;
  const u16 *Au = A, *Bu = Bm;
  float* Cu = Cv;
  if constexpr (MODE == 2) {
    const int t2 = swz & 127, h2 = swz >> 7;
    bm = t2 & 15; bn = 16 + (t2 >> 4);
    Au = A + h2 * 2048; Bu = Bm + h2 * 2048;
    Cu = Cv + (size_t)h2 * 4096 * 2048;
  } else {
    const int MBt = M >> 8;
    bm = swz % MBt; bn = swz / MBt;               // column-major tile order
  }
  const int m0 = bm << 8, n0 = bn << 8;

  const char* Ab = (const char*)Au;
  const char* Bb = (const char*)Bu;
  const size_t rowK = (size_t)K_ld * 2;           // bytes per input row
  const int srcx = ((lane & 7) ^ (lane >> 3)) << 4;  // pre-swizzled src col
  const int l3 = lane >> 3;
  const int tx = (t & 7) << 4;                    // read-side XOR (bytes)

  auto SToff = [&](int h, int j) -> int {
    int ii = w * 2 + j;
    return (ii < 8) ? (h * 64 + ii * 8) : (128 + h * 64 + (ii - 8) * 8);
  };
  auto STAGE_A = [&](int p, int T, int h) {
#pragma unroll
    for (int j = 0; j < 2; ++j) {
      int rb = SToff(h, j);
      GLDS(Ab + (size_t)(m0 + rb + l3) * rowK + (size_t)T * 128 + srcx,
           &SA0[p * 16384 + rb * 64]);
    }
  };
  auto STAGE_B = [&](int p, int T, int h) {
#pragma unroll
    for (int j = 0; j < 2; ++j) {
      int rb = SToff(h, j);
      GLDS(Bb + (size_t)(n0 + rb + l3) * rowK + (size_t)T * 128 + srcx,
           &SB0[p * 16384 + rb * 64]);
    }
  };
  auto LDA = [&](int p, int q, int fr, int kk) -> bf16x8 {
    int ar = wr * 128 + q * 32 + fr * 16 + t;
    const char* ptr = (const char*)&SA0[p * 16384] + ar * 128 + ((kk * 64 + 16 * g) ^ tx);
    return __builtin_bit_cast(bf16x8, *(const u16x8*)ptr);
  };
  auto LDB = [&](int p, int nf, int kk) -> bf16x8 {
    int br = wc * 64 + nf * 16 + t;
    const char* ptr = (const char*)&SB0[p * 16384] + br * 128 + ((kk * 64 + 16 * g) ^ tx);
    return __builtin_bit_cast(bf16x8, *(const u16x8*)ptr);
  };

  f32x4 acc[8][4];
#pragma unroll
  for (int i = 0; i < 8; ++i)
#pragma unroll
    for (int j = 0; j < 4; ++j) acc[i][j] = (f32x4){0.f, 0.f, 0.f, 0.f};
  bf16x8 bfr[4][2];
  bf16x8 afr[2][4];

  // prologue: T0 complete (8 loads) + T1.{A0,B0,B1} (6 loads)
  STAGE_A(0, 0, 0); STAGE_B(0, 0, 0); STAGE_A(0, 0, 1); STAGE_B(0, 0, 1);
  STAGE_A(1, 1, 0); STAGE_B(1, 1, 0); STAGE_B(1, 1, 1);
  VM6;                                            // T0 landed
  __builtin_amdgcn_s_barrier();

  const int NI = (K_len >> 7) - 1;
  for (int i = 0; i < NI; ++i) {
    const int T1 = 2 * i + 1, T2 = 2 * i + 2, T3 = 2 * i + 3;
    LOADB8(0); LOADA4(0, 0, 0);
    STAGE_A(1, T1, 1); LOADA4(0, 1, 1); MMA16(0, 0); BARX;
    STAGE_B(0, T2, 0); LOADA4(0, 2, 0); MMA16(1, 1); BARX;
    STAGE_B(0, T2, 1); LOADA4(0, 3, 1); MMA16(2, 0); BARX;
    STAGE_A(0, T2, 0); MMA16(3, 1); VM6; BARX;
    LOADB8(1); LOADA4(1, 0, 0);
    STAGE_A(0, T2, 1); LOADA4(1, 1, 1); MMA16(0, 0); BARX;
    STAGE_B(1, T3, 0); LOADA4(1, 2, 0); MMA16(1, 1); BARX;
    STAGE_A(1, T3, 0); LOADA4(1, 3, 1); MMA16(2, 0); BARX;
    STAGE_B(1, T3, 1); MMA16(3, 1); VM6; BARX;
  }
  {                                               // peeled final iteration
    const int TL_ = (K_len >> 6) - 1;
    LOADB8(0); LOADA4(0, 0, 0);
    STAGE_A(1, TL_, 1); LOADA4(0, 1, 1); MMA16(0, 0); BARX;
    LOADA4(0, 2, 0); MMA16(1, 1); BARX;
    LOADA4(0, 3, 1); MMA16(2, 0); BARX;
    MMA16(3, 1); VM0; BARX;
    LOADB8(1); LOADA4(1, 0, 0);
    LOADA4(1, 1, 1); MMA16(0, 0); BARX;
    LOADA4(1, 2, 0); MMA16(1, 1); BARX;
    LOADA4(1, 3, 1); MMA16(2, 0); BARX;
    MMA16(3, 1);
  }

  if constexpr (MODE == 0 || MODE == 2) {
    // fp32 C-write (row = 4*(lane>>4)+reg, col = lane&15)
    const int cstride = (MODE == 0) ? N : 2048;
    const int cbase   = (MODE == 0) ? n0 : (n0 - 4096);
#pragma unroll
    for (int fi = 0; fi < 8; ++fi)
#pragma unroll
      for (int nf = 0; nf < 4; ++nf)
#pragma unroll
        for (int r = 0; r < 4; ++r) {
          int row = m0 + wr * 128 + fi * 16 + 4 * g + r;
          int col = cbase + wc * 64 + nf * 16 + t;
          Cu[(size_t)row * cstride + col] = acc[fi][nf][r];
        }
  } else {
    // MODE 1: fused RoPE-Q epilogue (n0 < 4096 always)
    u16* TL = (u16*)LDSBUF;                       // [256][TLS]
    __syncthreads();                              // all LDS reads of K-loop done
#pragma unroll
    for (int fi = 0; fi < 8; ++fi)
#pragma unroll
      for (int nf = 0; nf < 4; ++nf)
#pragma unroll
        for (int r = 0; r < 4; ++r)
          TL[(wr * 128 + fi * 16 + 4 * g + r) * TLS + wc * 64 + nf * 16 + t] =
              f2bf(acc[fi][nf][r]);
    __syncthreads();

    const int j = lane;                           // 0..63 = pair index
    const float ifr = exp2f(-(float)j * L2_1E4_64);
#pragma unroll 1
    for (int it = 0; it < 64; ++it) {
      int combo = w * 64 + it;                    // 0..511
      int row = combo & 255;
      int hh = combo >> 8;                        // 0/1: head within tile
      int tok = m0 + row;
      int b = tok >> 11, s = tok & (Ssz - 1);
      float x1 = bf2f(TL[row * TLS + hh * 128 + j]);
      float x2 = bf2f(TL[row * TLS + hh * 128 + 64 + j]);
      float p = (float)pos[tok];
      float ang = p * ifr;
      float sn, cs;
      __sincosf(ang, &sn, &cs);
      float o1 = (x1 * cs - x2 * sn) * QSCALE;
      float o2 = (x2 * cs + x1 * sn) * QSCALE;
      int h = (n0 >> 7) + hh;
      u16* o = Qr + ((size_t)(b * Hsz + h) * Ssz + s) * Dsz;
      o[j] = f2bf(o1); o[j + 64] = f2bf(o2);
    }
  }
}

// --------- K-region: sum K-split partials + RoPE -> Kr[b][kvh][s][d] --------
__global__ __launch_bounds__(256) void k_ropeK2(const float* __restrict__ Cp,
                                                const int* __restrict__ pos,
                                                u16* __restrict__ Kr) {
  int idx = blockIdx.x * 256 + threadIdx.x;       // B*S*KV*64
  if (idx >= Bsz * Ssz * KVsz * 64) return;
  const size_t OFF2 = (size_t)4096 * 2048;
  int j = idx & 63;
  int kvh = (idx >> 6) & 7;
  int bs = idx >> 9;                              // 0..4095
  size_t p0 = (size_t)bs * 2048 + kvh * 128 + j;
  float x1 = Cp[p0] + Cp[p0 + OFF2];
  float x2 = Cp[p0 + 64] + Cp[p0 + 64 + OFF2];
  float p = (float)pos[bs];
  float ang = p * exp2f(-(float)j * L2_1E4_64);
  float sn, cs;
  __sincosf(ang, &sn, &cs);
  int b = bs >> 11, sidx = bs & (Ssz - 1);
  u16* o = Kr + ((size_t)(b * KVsz + kvh) * Ssz + sidx) * Dsz;
  o[j] = f2bf(x1 * cs - x2 * sn);
  o[j + 64] = f2bf(x2 * cs + x1 * sn);
}

// --------- V-region: sum partials + LDS transpose -> Vt[bk][d][s] -----------
__global__ __launch_bounds__(256) void k_vtrans2(const float* __restrict__ Cp,
                                                 u16* __restrict__ Vt) {
  __shared__ __align__(16) u16 Tl[64 * 72];
  const int tid = threadIdx.x;
  const int bk = blockIdx.y;                      // b*KV + kvh
  const int s0 = (blockIdx.x >> 1) * 64;
  const int d0 = (blockIdx.x & 1) * 64;
  const int b = bk >> 3, kvh = bk & 7;
  const size_t OFF2 = (size_t)4096 * 2048;
  const size_t base = (size_t)(b * Ssz + s0) * 2048 + 1024 + kvh * 128 + d0;
#pragma unroll
  for (int p = 0; p < 2; ++p) {
    int cid = p * 256 + tid;
    int r = cid >> 3, co = cid & 7;
    int chunk = co ^ ((r >> 3) & 7);
    const float* s1 = Cp + base + (size_t)r * 2048 + co * 8;
    u16x8 v;
#pragma unroll
    for (int e = 0; e < 8; ++e) v[e] = f2bf(s1[e] + s1[OFF2 + e]);
    *(u16x8*)((char*)Tl + r * 144 + chunk * 16) = v;
  }
  __syncthreads();
#pragma unroll
  for (int p = 0; p < 2; ++p) {
    int cid = p * 256 + tid;
    int dr = cid >> 3, c = cid & 7;
    u16x8 v;
#pragma unroll
    for (int j = 0; j < 8; ++j) {
      int s = 8 * c + j;
      v[j] = *(const u16*)((char*)Tl + s * 144 + (((dr >> 3) ^ c) * 16) + (dr & 7) * 2);
    }
    *(u16x8*)(Vt + ((size_t)bk * Dsz + d0 + dr) * Ssz + s0 + 8 * c) = v;
  }
}

// ---------------- flash attention: 4-wave swapped-QK^T 32x32 ----------------
// r15: REVERT to r13 structure (r14's 3-buffer counted-vmcnt regressed: loads
// already land under the ~2000cy tile compute, and runtime buffer index broke
// static addressing -> VALU 25->40%). r13 = 256-thread blocks (4 waves, 128
// q-rows), 2 blocks/CU, compile-time double-buffer, triangle fold uniform 34
// tiles. One delta vs r13: defer-max threshold 4 -> 8 (T13/HK value).
__global__ __launch_bounds__(256, 2) void k_attn(const u16* __restrict__ Qr,
                                                 const u16* __restrict__ Kr,
                                                 const u16* __restrict__ Vt,
                                                 u16* __restrict__ AO) {
  __shared__ __align__(16) u16 Kl[2][64 * 128];  // [k][d] swizzled (32KB)
  __shared__ __align__(16) u16 Vl[2][128 * 64];  // [d][k] swizzled (32KB)
  const int tid = threadIdx.x;                   // 0..255
  const int w = tid >> 6, lane = tid & 63;       // w: 0..3
  const int q = lane & 31, hi = lane >> 5;
  const int bh = blockIdx.y;
  const int b = bh >> 5, h = bh & 31;
  const int kvh = h >> 2;                        // GQA: H/KV = 4
  const int bx = blockIdx.x;                     // 0..7

  // loop-invariant LDS read byte-offsets (statically indexed -> registers)
  const int xq = (q & 7) << 4;
  int koff[8][2], voff[4][4];
#pragma unroll
  for (int ds = 0; ds < 8; ++ds) {
    int c = (ds * 32 + hi * 16) ^ xq;
    koff[ds][0] = q * 256 + c;
    koff[ds][1] = (32 + q) * 256 + c;
  }
#pragma unroll
  for (int ks = 0; ks < 4; ++ks) {
    int c = (ks * 32 + hi * 16) ^ xq;
#pragma unroll
    for (int dt = 0; dt < 4; ++dt)
      voff[ks][dt] = (dt * 32 + q) * 128 + c;
  }

  const char* Kbase = (const char*)(Kr + (size_t)(b * KVsz + kvh) * Ssz * Dsz);
  const char* Vbase = (const char*)(Vt + (size_t)(b * KVsz + kvh) * Dsz * Ssz);

  auto STAGE = [&](int bu, int kt2) {            // 256 threads: 4+4 GLDS each
    const char* Kb = Kbase + (size_t)kt2 * (64 * 256);
    const char* Vb = Vbase + (size_t)kt2 * 128;   // 64 cols * 2B
#pragma unroll
    for (int j = 0; j < 4; ++j) {
      int flat = j * 256 + tid;
      int row = flat >> 4, colb = ((flat & 15) * 16) ^ ((row & 7) << 4);
      GLDS(Kb + (size_t)row * 256 + colb, (char*)&Kl[bu][0] + flat * 16);
    }
#pragma unroll
    for (int j = 0; j < 4; ++j) {
      int flat = j * 256 + tid;
      int row = flat >> 3, colb = ((flat & 7) * 16) ^ ((row & 7) << 4);
      GLDS(Vb + (size_t)row * (Ssz * 2) + colb, (char*)&Vl[bu][0] + flat * 16);
    }
  };

#pragma unroll 1
  for (int pass = 0; pass < 2; ++pass) {
    const int bxr = pass ? bx : (15 - bx);       // q-tile index (128 rows)
    const int q0 = bxr * 128;
    const int qw = q0 + w * 32;
    const int ntiles = 2 * bxr + 2;              // always even
    const int qg = qw + q;

    const u16* Qb = Qr + ((size_t)bh * Ssz + qw + q) * Dsz + hi * 8;
    bf16x8 qf[8];
#pragma unroll
    for (int ds = 0; ds < 8; ++ds)
      qf[ds] = __builtin_bit_cast(bf16x8, *(const u16x8*)(Qb + ds * 16));

    f32x16 oacc[4];
#pragma unroll
    for (int dt = 0; dt < 4; ++dt)
#pragma unroll
      for (int r = 0; r < 16; ++r) oacc[dt][r] = 0.f;
    float mr = -1e30f, lr = 0.f;

    STAGE(0, 0);
    __syncthreads();

    auto TILE = [&](int bufc, int kt) {
      const int k0 = kt * 64;
      if (kt + 1 < ntiles) STAGE(bufc ^ 1, kt + 1);  // prefetch overlaps compute

      if (k0 <= qw + 31) {                           // wave participates
        const char* Kb = (const char*)&Kl[bufc][0];
        const char* Vb = (const char*)&Vl[bufc][0];
        f32x16 pa0, pa1;
#pragma unroll
        for (int r = 0; r < 16; ++r) { pa0[r] = 0.f; pa1[r] = 0.f; }
        __builtin_amdgcn_s_setprio(1);
#pragma unroll
        for (int ds = 0; ds < 8; ++ds) {
          bf16x8 kf0 = __builtin_bit_cast(bf16x8, *(const u16x8*)(Kb + koff[ds][0]));
          pa0 = __builtin_amdgcn_mfma_f32_32x32x16_bf16(kf0, qf[ds], pa0, 0, 0, 0);
          bf16x8 kf1 = __builtin_bit_cast(bf16x8, *(const u16x8*)(Kb + koff[ds][1]));
          pa1 = __builtin_amdgcn_mfma_f32_32x32x16_bf16(kf1, qf[ds], pa1, 0, 0, 0);
        }
        __builtin_amdgcn_s_setprio(0);

        if (k0 + 63 > qw) {                          // causal mask (tail tiles)
#pragma unroll
          for (int reg = 0; reg < 16; ++reg) {
            const int kb = (reg & 3) + 8 * (reg >> 2) + 4 * hi;
            if (k0 + kb > qg)      pa0[reg] = -1e30f;
            if (k0 + 32 + kb > qg) pa1[reg] = -1e30f;
          }
        }
        float tmx[16];
#pragma unroll
        for (int i = 0; i < 16; ++i) tmx[i] = fmaxf(pa0[i], pa1[i]);
#pragma unroll
        for (int s = 8; s > 0; s >>= 1)
#pragma unroll
          for (int i = 0; i < s; ++i) tmx[i] = fmaxf(tmx[i], tmx[i + s]);
        const float mx = fmaxf(tmx[0], __shfl_xor(tmx[0], 32, 64));
        if (!__all(mx <= mr + 8.0f)) {               // T13 defer-max (THR=8)
          const float mnew = fmaxf(mr, mx);
          const float corr = exp2f(mr - mnew);
          lr *= corr;
#pragma unroll
          for (int dt = 0; dt < 4; ++dt)
#pragma unroll
            for (int reg = 0; reg < 16; ++reg) oacc[dt][reg] *= corr;
          mr = mnew;
        }
        float su[16];
#pragma unroll
        for (int reg = 0; reg < 16; ++reg) {
          pa0[reg] = exp2f(pa0[reg] - mr);
          pa1[reg] = exp2f(pa1[reg] - mr);
          su[reg] = pa0[reg] + pa1[reg];
        }
#pragma unroll
        for (int s = 8; s > 0; s >>= 1)
#pragma unroll
          for (int i = 0; i < s; ++i) su[i] += su[i + s];
        lr += su[0] + __shfl_xor(su[0], 32, 64);

        uint32_t W0[4][2], W1[4][2];
#pragma unroll
        for (int r2 = 0; r2 < 4; ++r2)
#pragma unroll
          for (int c = 0; c < 2; ++c) {
            W0[r2][c] = packc(pa0[4 * r2 + 2 * c], pa0[4 * r2 + 2 * c + 1]);
            W1[r2][c] = packc(pa1[4 * r2 + 2 * c], pa1[4 * r2 + 2 * c + 1]);
          }

        __builtin_amdgcn_s_setprio(1);
#pragma unroll
        for (int ks = 0; ks < 4; ++ks) {
          const int T = ks >> 1, r2e = 2 * (ks & 1);
          uint32_t a0 = T ? W1[r2e][0]     : W0[r2e][0];
          uint32_t a1 = T ? W1[r2e][1]     : W0[r2e][1];
          uint32_t b0 = T ? W1[r2e + 1][0] : W0[r2e + 1][0];
          uint32_t b1 = T ? W1[r2e + 1][1] : W0[r2e + 1][1];
          asm("v_permlane32_swap_b32 %0, %1" : "+v"(a0), "+v"(b0));
          asm("v_permlane32_swap_b32 %0, %1" : "+v"(a1), "+v"(b1));
          u32x4 fw; fw[0] = a0; fw[1] = a1; fw[2] = b0; fw[3] = b1;
          bf16x8 pf = __builtin_bit_cast(bf16x8, fw);
#pragma unroll
          for (int dt = 0; dt < 4; ++dt) {
            bf16x8 vf = __builtin_bit_cast(bf16x8, *(const u16x8*)(Vb + voff[ks][dt]));
            oacc[dt] = __builtin_amdgcn_mfma_f32_32x32x16_bf16(vf, pf, oacc[dt], 0, 0, 0);
          }
        }
        __builtin_amdgcn_s_setprio(0);
      }
      __syncthreads();                               // drains vmcnt: next buf ready
    };

    for (int kt = 0; kt < ntiles; kt += 2) {         // ntiles % 2 == 0 always
      TILE(0, kt);
      TILE(1, kt + 1);
    }

    const float inv = 1.f / lr;
    u16* Ob = AO + ((size_t)(b * Ssz) + qw + q) * HIDsz + h * Dsz + hi * 4;
#pragma unroll
    for (int dt = 0; dt < 4; ++dt)
#pragma unroll
      for (int r2 = 0; r2 < 4; ++r2) {
        u16x4 o4;
#pragma unroll
        for (int j = 0; j < 4; ++j) o4[j] = f2bf(oacc[dt][4 * r2 + j] * inv);
        *(u16x4*)(Ob + dt * 32 + r2 * 8) = o4;
      }
    // pass-1 epilogue touches only global memory; last TILE's barrier already
    // ordered all LDS reads before pass-2's STAGE overwrite -> no extra sync.
  }
}

// ---------------- host ----------------
extern "C" void kernel_launch(void* const* d_in, const int* in_sizes, int n_in,
                              void* d_out, int out_size, void* d_ws, size_t ws_size,
                              hipStream_t stream) {
  (void)in_sizes; (void)n_in; (void)out_size;
  const float* hs   = (const float*)d_in[0];
  const int*   pos  = (const int*)d_in[1];
  const float* Wqkv = (const float*)d_in[2];
  const float* Wo   = (const float*)d_in[3];

  char* ws = (char*)d_ws;
  const size_t SZ_XBF = (size_t)4096 * 4096 * 2;   // also reused for AO
  const size_t SZ_WQ  = (size_t)6144 * 4096 * 2;
  const size_t SZ_WO  = (size_t)4096 * 4096 * 2;
  const size_t SZ_QR  = (size_t)Bsz * Hsz * Ssz * Dsz * 2;
  const size_t SZ_KR  = (size_t)Bsz * KVsz * Ssz * Dsz * 2;
  const size_t SZ_VT  = SZ_KR;

  size_t off = 0;
  u16*   Xbf   = (u16*)(ws + off);  off += SZ_XBF;
  u16*   Wq_bf = (u16*)(ws + off);  off += SZ_WQ;
  u16*   Wo_bf = (u16*)(ws + off);  off += SZ_WO;
  u16*   Qr    = (u16*)(ws + off);  off += SZ_QR;
  u16*   Kr    = (u16*)(ws + off);  off += SZ_KR;
  u16*   Vt    = (u16*)(ws + off);  off += SZ_VT;
  u16*   AO    = Xbf;                               // alias (Xbf dead after gemm1)
  float* Cp    = (float*)d_out;                     // K-split partials: d_out as
                                                    // scratch, fully overwritten
                                                    // by gemm2 afterwards
  if (ws_size < off) return;                        // fail loudly

  // 1. fp32 -> bf16 conversions (single launch)
  k_cvt3<<<(N4_HS + N4_WQ + N4_WO + 255) / 256, 256, 0, stream>>>(
      hs, Wqkv, Wo, Xbf, Wq_bf, Wo_bf);

  // 2a. QKV projection, Q region (256 blocks, 1 clean round) + RoPE-Q -> Qr
  k_gemm256<1><<<256, 512, 0, stream>>>(Xbf, Wq_bf, nullptr, pos, Qr,
                                        Bsz * Ssz, NQKV, HIDsz, HIDsz);

  // 2b. K/V region K-split partials (256 blocks, 1 clean half-round) -> Cp
  k_gemm256<2><<<256, 512, 0, stream>>>(Xbf, Wq_bf, Cp, nullptr, nullptr,
                                        Bsz * Ssz, NQKV, HIDsz, 2048);

  // 2c. sum partials + RoPE-K -> Kr ; sum + transpose -> Vt
  k_ropeK2<<<(Bsz * Ssz * KVsz * 64) / 256, 256, 0, stream>>>(Cp, pos, Kr);
  k_vtrans2<<<dim3(64, Bsz * KVsz), 256, 0, stream>>>(Cp, Vt);

  // 3. causal GQA attention (folded triangle, 2 blocks/CU TLP) -> AO
  k_attn<<<dim3(8, Bsz * Hsz), 256, 0, stream>>>(Qr, Kr, Vt, AO);

  // 4. o_proj: [4096,4096] x [4096,4096]^T -> d_out fp32 (overwrites scratch)
  k_gemm256<0><<<256, 512, 0, stream>>>(AO, Wo_bf, (float*)d_out, nullptr,
                                        nullptr, Bsz * Ssz, HIDsz, HIDsz, HIDsz);
}

// Round 16
// 451.722 us; speedup vs baseline: 1.0488x; 1.0152x over previous
//
#include <hip/hip_runtime.h>
#include <stdint.h>
#include <stddef.h>

#define Bsz   2
#define Ssz   2048
#define HIDsz 4096
#define Hsz   32
#define KVsz  8
#define Dsz   128
#define NQKV  6144                     // (H+2KV)*D
// Q scale = 1/sqrt(128) * log2(e): softmax computed base-2 (exp2 is the HW op)
#define QSCALE 0.12752057463f
#define L2_1E4_64 0.20762050595f       // log2(10000)/64

typedef __bf16 bf16x8 __attribute__((ext_vector_type(8)));
typedef __bf16 bf16x2 __attribute__((ext_vector_type(2)));
typedef float  f32x4  __attribute__((ext_vector_type(4)));
typedef float  f32x16 __attribute__((ext_vector_type(16)));
typedef unsigned short u16;
typedef u16 u16x4 __attribute__((ext_vector_type(4)));
typedef u16 u16x8 __attribute__((ext_vector_type(8)));
typedef uint32_t u32x4 __attribute__((ext_vector_type(4)));

__device__ __forceinline__ u16 f2bf(float f) {
  uint32_t u = __builtin_bit_cast(uint32_t, f);
  u = (u + 0x7FFFu + ((u >> 16) & 1u)) >> 16;   // RNE
  return (u16)u;
}
__device__ __forceinline__ float bf2f(u16 h) {
  return __builtin_bit_cast(float, (uint32_t)h << 16);
}
// pair pack via compiler (emits v_cvt_pk_bf16_f32)
__device__ __forceinline__ uint32_t packc(float lo, float hi_) {
  bf16x2 t;
  t[0] = (__bf16)lo; t[1] = (__bf16)hi_;
  return __builtin_bit_cast(uint32_t, t);
}

// global -> LDS async copy, 16B per lane; LDS dest = wave-uniform base + lane*16
#define GLDS(gp, lp) __builtin_amdgcn_global_load_lds( \
    (__attribute__((address_space(1))) void*)(void*)(gp), \
    (__attribute__((address_space(3))) void*)(lp), 16, 0, 0)

// ---------------- fused fp32->bf16 conversion (one launch, 3 tensors) -------
#define N4_HS  ((Bsz * Ssz * HIDsz) / 4)
#define N4_WQ  ((NQKV * HIDsz) / 4)
#define N4_WO  ((HIDsz * HIDsz) / 4)
__global__ __launch_bounds__(256) void k_cvt3(const float* __restrict__ hs,
                                              const float* __restrict__ wqkv,
                                              const float* __restrict__ wo,
                                              u16* __restrict__ xbf,
                                              u16* __restrict__ wqbf,
                                              u16* __restrict__ wobf) {
  int i = blockIdx.x * 256 + threadIdx.x;
  const float* src; u16* dst; int off;
  if (i < N4_HS)                   { src = hs;   dst = xbf;  off = i; }
  else if (i < N4_HS + N4_WQ)      { src = wqkv; dst = wqbf; off = i - N4_HS; }
  else if (i < N4_HS + N4_WQ + N4_WO) { src = wo; dst = wobf; off = i - N4_HS - N4_WQ; }
  else return;
  float4 v = ((const float4*)src)[off];
  u16x4 o;
  o.x = f2bf(v.x); o.y = f2bf(v.y); o.z = f2bf(v.z); o.w = f2bf(v.w);
  ((u16x4*)dst)[off] = o;
}

// ============ 256x256 8-phase GEMM core (shared macros) ============
#define BARX do { asm volatile("" ::: "memory"); __builtin_amdgcn_s_barrier(); \
                  asm volatile("" ::: "memory"); } while (0)
#define VM6  asm volatile("s_waitcnt vmcnt(6)" ::: "memory")
#define VM0  asm volatile("s_waitcnt vmcnt(0)" ::: "memory")

#define LOADA4(P_, Q_, F_) do {                                               \
    afr[F_][0] = LDA(P_, Q_, 0, 0); afr[F_][1] = LDA(P_, Q_, 0, 1);           \
    afr[F_][2] = LDA(P_, Q_, 1, 0); afr[F_][3] = LDA(P_, Q_, 1, 1);           \
  } while (0)

#define LOADB8(P_) do {                                                       \
    _Pragma("unroll") for (int nf = 0; nf < 4; ++nf) {                        \
      bfr[nf][0] = LDB(P_, nf, 0); bfr[nf][1] = LDB(P_, nf, 1); }             \
  } while (0)

#define MMA16(Q_, F_) do {                                                    \
    __builtin_amdgcn_s_setprio(1);                                            \
    _Pragma("unroll") for (int nf = 0; nf < 4; ++nf) {                        \
      acc[(Q_)*2][nf]   = __builtin_amdgcn_mfma_f32_16x16x32_bf16(afr[F_][0], bfr[nf][0], acc[(Q_)*2][nf],   0,0,0); \
      acc[(Q_)*2+1][nf] = __builtin_amdgcn_mfma_f32_16x16x32_bf16(afr[F_][2], bfr[nf][0], acc[(Q_)*2+1][nf], 0,0,0); \
    }                                                                         \
    _Pragma("unroll") for (int nf = 0; nf < 4; ++nf) {                        \
      acc[(Q_)*2][nf]   = __builtin_amdgcn_mfma_f32_16x16x32_bf16(afr[F_][1], bfr[nf][1], acc[(Q_)*2][nf],   0,0,0); \
      acc[(Q_)*2+1][nf] = __builtin_amdgcn_mfma_f32_16x16x32_bf16(afr[F_][3], bfr[nf][1], acc[(Q_)*2+1][nf], 0,0,0); \
    }                                                                         \
    __builtin_amdgcn_s_setprio(0);                                            \
  } while (0)

// Shared K-loop body (identical ledger to r5-r15; KL = 4096 or 2048)
#define GEMM_KLOOP(KL_)                                                       \
  STAGE_A(0, 0, 0); STAGE_B(0, 0, 0); STAGE_A(0, 0, 1); STAGE_B(0, 0, 1);     \
  STAGE_A(1, 1, 0); STAGE_B(1, 1, 0); STAGE_B(1, 1, 1);                       \
  VM6;                                                                        \
  __builtin_amdgcn_s_barrier();                                               \
  const int NI = ((KL_) >> 7) - 1;                                            \
  for (int i = 0; i < NI; ++i) {                                              \
    const int T1 = 2 * i + 1, T2 = 2 * i + 2, T3 = 2 * i + 3;                 \
    LOADB8(0); LOADA4(0, 0, 0);                                               \
    STAGE_A(1, T1, 1); LOADA4(0, 1, 1); MMA16(0, 0); BARX;                    \
    STAGE_B(0, T2, 0); LOADA4(0, 2, 0); MMA16(1, 1); BARX;                    \
    STAGE_B(0, T2, 1); LOADA4(0, 3, 1); MMA16(2, 0); BARX;                    \
    STAGE_A(0, T2, 0); MMA16(3, 1); VM6; BARX;                                \
    LOADB8(1); LOADA4(1, 0, 0);                                               \
    STAGE_A(0, T2, 1); LOADA4(1, 1, 1); MMA16(0, 0); BARX;                    \
    STAGE_B(1, T3, 0); LOADA4(1, 2, 0); MMA16(1, 1); BARX;                    \
    STAGE_A(1, T3, 0); LOADA4(1, 3, 1); MMA16(2, 0); BARX;                    \
    STAGE_B(1, T3, 1); MMA16(3, 1); VM6; BARX;                                \
  }                                                                           \
  {                                                                           \
    const int TL_ = ((KL_) >> 6) - 1;                                         \
    LOADB8(0); LOADA4(0, 0, 0);                                               \
    STAGE_A(1, TL_, 1); LOADA4(0, 1, 1); MMA16(0, 0); BARX;                   \
    LOADA4(0, 2, 0); MMA16(1, 1); BARX;                                       \
    LOADA4(0, 3, 1); MMA16(2, 0); BARX;                                       \
    MMA16(3, 1); VM0; BARX;                                                   \
    LOADB8(1); LOADA4(1, 0, 0);                                               \
    LOADA4(1, 1, 1); MMA16(0, 0); BARX;                                       \
    LOADA4(1, 2, 0); MMA16(1, 1); BARX;                                       \
    LOADA4(1, 3, 1); MMA16(2, 0); BARX;                                       \
    MMA16(3, 1);                                                              \
  }

#define GEMM_PREAMBLE(Au_, Bu_, KLD_)                                         \
  const char* Ab = (const char*)(Au_);                                        \
  const char* Bb = (const char*)(Bu_);                                        \
  const size_t rowK = (size_t)(KLD_) * 2;                                     \
  const int srcx = ((lane & 7) ^ (lane >> 3)) << 4;                           \
  const int l3 = lane >> 3;                                                   \
  const int tx = (t & 7) << 4;                                                \
  auto SToff = [&](int h, int j) -> int {                                     \
    int ii = w * 2 + j;                                                       \
    return (ii < 8) ? (h * 64 + ii * 8) : (128 + h * 64 + (ii - 8) * 8);      \
  };                                                                          \
  auto STAGE_A = [&](int p, int T, int h) {                                   \
    _Pragma("unroll") for (int j = 0; j < 2; ++j) {                           \
      int rb = SToff(h, j);                                                   \
      GLDS(Ab + (size_t)(m0 + rb + l3) * rowK + (size_t)T * 128 + srcx,       \
           &SA0[p * 16384 + rb * 64]);                                        \
    }                                                                         \
  };                                                                          \
  auto STAGE_B = [&](int p, int T, int h) {                                   \
    _Pragma("unroll") for (int j = 0; j < 2; ++j) {                           \
      int rb = SToff(h, j);                                                   \
      GLDS(Bb + (size_t)(n0 + rb + l3) * rowK + (size_t)T * 128 + srcx,       \
           &SB0[p * 16384 + rb * 64]);                                        \
    }                                                                         \
  };                                                                          \
  auto LDA = [&](int p, int q, int fr, int kk) -> bf16x8 {                    \
    int ar = wr * 128 + q * 32 + fr * 16 + t;                                 \
    const char* ptr = (const char*)&SA0[p * 16384] + ar * 128 +               \
                      ((kk * 64 + 16 * g) ^ tx);                              \
    return __builtin_bit_cast(bf16x8, *(const u16x8*)ptr);                    \
  };                                                                          \
  auto LDB = [&](int p, int nf, int kk) -> bf16x8 {                           \
    int br = wc * 64 + nf * 16 + t;                                           \
    const char* ptr = (const char*)&SB0[p * 16384] + br * 128 +               \
                      ((kk * 64 + 16 * g) ^ tx);                              \
    return __builtin_bit_cast(bf16x8, *(const u16x8*)ptr);                    \
  };                                                                          \
  f32x4 acc[8][4];                                                            \
  _Pragma("unroll") for (int i = 0; i < 8; ++i)                               \
    _Pragma("unroll") for (int j = 0; j < 4; ++j)                             \
      acc[i][j] = (f32x4){0.f, 0.f, 0.f, 0.f};                                \
  bf16x8 bfr[4][2];                                                           \
  bf16x8 afr[2][4];

#define TLS 258                         // RoPE-Q epilogue LDS tile stride (u16)

// ---- merged QKV projection: blocks 0..255 = Q (K=4096, RoPE-Q epilogue);
// ---- blocks 256..511 = K/V K-split halves (K=2048, fp32 strip epilogue).
// Dispatch order: Q blocks first (uniform T) fill all 256 CUs; KV blocks
// (T/2) backfill -> wall = 1.5T with no pairing hazard, one launch bubble
// saved vs r15's two launches. XCD swizzle applied within each half.
__global__ __launch_bounds__(512, 1) void k_gemmQKV(const u16* __restrict__ A,
                                                    const u16* __restrict__ Bm,
                                                    float* __restrict__ Cv,
                                                    const int* __restrict__ pos,
                                                    u16* __restrict__ Qr) {
  __shared__ __align__(16) char LDSBUF[256 * TLS * 2];
  u16* SA0 = (u16*)LDSBUF;                        // SA[2][256*64]
  u16* SB0 = (u16*)(LDSBUF + 65536);              // SB[2][256*64]
  const int tid = threadIdx.x;
  const int w = tid >> 6, lane = tid & 63;
  const int g = lane >> 4, t = lane & 15;
  const int wr = w >> 2, wc = w & 3;
  const int bi = blockIdx.x;
  const bool isQ = (bi < 256);
  const int hb = bi & 255;
  const int swz = (hb & 7) * 32 + (hb >> 3);      // XCD swizzle within half

  int bm, bn;
  const u16 *Au = A, *Bu = Bm;
  float* Cu = Cv;
  if (isQ) {
    bm = swz % 16; bn = swz / 16;                 // column-major tile order
  } else {
    const int t2 = swz & 127, h2 = swz >> 7;
    bm = t2 & 15; bn = 16 + (t2 >> 4);
    Au = A + h2 * 2048; Bu = Bm + h2 * 2048;
    Cu = Cv + (size_t)h2 * 4096 * 2048;
  }
  const int m0 = bm << 8, n0 = bn << 8;

  GEMM_PREAMBLE(Au, Bu, HIDsz)

  if (isQ) { GEMM_KLOOP(4096) }
  else     { GEMM_KLOOP(2048) }

  if (!isQ) {
    // fp32 strip write (row = 4*(lane>>4)+reg, col = lane&15)
    const int cbase = n0 - 4096;
#pragma unroll
    for (int fi = 0; fi < 8; ++fi)
#pragma unroll
      for (int nf = 0; nf < 4; ++nf)
#pragma unroll
        for (int r = 0; r < 4; ++r) {
          int row = m0 + wr * 128 + fi * 16 + 4 * g + r;
          int col = cbase + wc * 64 + nf * 16 + t;
          Cu[(size_t)row * 2048 + col] = acc[fi][nf][r];
        }
  } else {
    // fused RoPE-Q epilogue
    u16* TL = (u16*)LDSBUF;                       // [256][TLS]
    __syncthreads();                              // all LDS reads of K-loop done
#pragma unroll
    for (int fi = 0; fi < 8; ++fi)
#pragma unroll
      for (int nf = 0; nf < 4; ++nf)
#pragma unroll
        for (int r = 0; r < 4; ++r)
          TL[(wr * 128 + fi * 16 + 4 * g + r) * TLS + wc * 64 + nf * 16 + t] =
              f2bf(acc[fi][nf][r]);
    __syncthreads();

    const int j = lane;                           // 0..63 = pair index
    const float ifr = exp2f(-(float)j * L2_1E4_64);
#pragma unroll 1
    for (int it = 0; it < 64; ++it) {
      int combo = w * 64 + it;                    // 0..511
      int row = combo & 255;
      int hh = combo >> 8;                        // 0/1: head within tile
      int tok = m0 + row;
      int b = tok >> 11, s = tok & (Ssz - 1);
      float x1 = bf2f(TL[row * TLS + hh * 128 + j]);
      float x2 = bf2f(TL[row * TLS + hh * 128 + 64 + j]);
      float p = (float)pos[tok];
      float ang = p * ifr;
      float sn, cs;
      __sincosf(ang, &sn, &cs);
      float o1 = (x1 * cs - x2 * sn) * QSCALE;
      float o2 = (x2 * cs + x1 * sn) * QSCALE;
      int h = (n0 >> 7) + hh;
      u16* o = Qr + ((size_t)(b * Hsz + h) * Ssz + s) * Dsz;
      o[j] = f2bf(o1); o[j + 64] = f2bf(o2);
    }
  }
}

// ---- o_proj GEMM (plain fp32 C-write), grid 256, K=4096 ----
__global__ __launch_bounds__(512, 1) void k_gemmO(const u16* __restrict__ A,
                                                  const u16* __restrict__ Bm,
                                                  float* __restrict__ Cv) {
  __shared__ __align__(16) char LDSBUF[4 * 256 * 64 * 2];
  u16* SA0 = (u16*)LDSBUF;
  u16* SB0 = (u16*)(LDSBUF + 65536);
  const int tid = threadIdx.x;
  const int w = tid >> 6, lane = tid & 63;
  const int g = lane >> 4, t = lane & 15;
  const int wr = w >> 2, wc = w & 3;
  const int swz = (blockIdx.x & 7) * 32 + (blockIdx.x >> 3);
  const int bm = swz % 16, bn = swz / 16;         // column-major tile order
  const int m0 = bm << 8, n0 = bn << 8;

  GEMM_PREAMBLE(A, Bm, HIDsz)
  GEMM_KLOOP(4096)

#pragma unroll
  for (int fi = 0; fi < 8; ++fi)
#pragma unroll
    for (int nf = 0; nf < 4; ++nf)
#pragma unroll
      for (int r = 0; r < 4; ++r) {
        int row = m0 + wr * 128 + fi * 16 + 4 * g + r;
        int col = n0 + wc * 64 + nf * 16 + t;
        Cv[(size_t)row * HIDsz + col] = acc[fi][nf][r];
      }
}

// ---- merged K/V fixup: blocks 0..8191 = RoPE-K; 8192..9215 = V-transpose ----
__global__ __launch_bounds__(256) void k_fixKV(const float* __restrict__ Cp,
                                               const int* __restrict__ pos,
                                               u16* __restrict__ Kr,
                                               u16* __restrict__ Vt) {
  const size_t OFF2 = (size_t)4096 * 2048;
  if (blockIdx.x < 8192) {
    int idx = blockIdx.x * 256 + threadIdx.x;     // B*S*KV*64
    int j = idx & 63;
    int kvh = (idx >> 6) & 7;
    int bs = idx >> 9;                            // 0..4095
    size_t p0 = (size_t)bs * 2048 + kvh * 128 + j;
    float x1 = Cp[p0] + Cp[p0 + OFF2];
    float x2 = Cp[p0 + 64] + Cp[p0 + 64 + OFF2];
    float p = (float)pos[bs];
    float ang = p * exp2f(-(float)j * L2_1E4_64);
    float sn, cs;
    __sincosf(ang, &sn, &cs);
    int b = bs >> 11, sidx = bs & (Ssz - 1);
    u16* o = Kr + ((size_t)(b * KVsz + kvh) * Ssz + sidx) * Dsz;
    o[j] = f2bf(x1 * cs - x2 * sn);
    o[j + 64] = f2bf(x2 * cs + x1 * sn);
  } else {
    __shared__ __align__(16) u16 Tl[64 * 72];
    const int vb = blockIdx.x - 8192;             // 0..1023
    const int tid = threadIdx.x;
    const int bk = vb >> 6;                       // b*KV + kvh
    const int bx = vb & 63;
    const int s0 = (bx >> 1) * 64;
    const int d0 = (bx & 1) * 64;
    const int b = bk >> 3, kvh = bk & 7;
    const size_t base = (size_t)(b * Ssz + s0) * 2048 + 1024 + kvh * 128 + d0;
#pragma unroll
    for (int p = 0; p < 2; ++p) {
      int cid = p * 256 + tid;
      int r = cid >> 3, co = cid & 7;
      int chunk = co ^ ((r >> 3) & 7);
      const float* s1 = Cp + base + (size_t)r * 2048 + co * 8;
      u16x8 v;
#pragma unroll
      for (int e = 0; e < 8; ++e) v[e] = f2bf(s1[e] + s1[OFF2 + e]);
      *(u16x8*)((char*)Tl + r * 144 + chunk * 16) = v;
    }
    __syncthreads();
#pragma unroll
    for (int p = 0; p < 2; ++p) {
      int cid = p * 256 + tid;
      int dr = cid >> 3, c = cid & 7;
      u16x8 v;
#pragma unroll
      for (int j = 0; j < 8; ++j) {
        int s = 8 * c + j;
        v[j] = *(const u16*)((char*)Tl + s * 144 + (((dr >> 3) ^ c) * 16) + (dr & 7) * 2);
      }
      *(u16x8*)(Vt + ((size_t)bk * Dsz + d0 + dr) * Ssz + s0 + 8 * c) = v;
    }
  }
}

// ---------------- flash attention: 4-wave swapped-QK^T 32x32 ----------------
// r13/r15 structure (best measured): 256-thread blocks (4 waves, 128 q-rows),
// 2 blocks/CU TLP, compile-time double-buffer, triangle fold uniform 34 tiles.
__global__ __launch_bounds__(256, 2) void k_attn(const u16* __restrict__ Qr,
                                                 const u16* __restrict__ Kr,
                                                 const u16* __restrict__ Vt,
                                                 u16* __restrict__ AO) {
  __shared__ __align__(16) u16 Kl[2][64 * 128];  // [k][d] swizzled (32KB)
  __shared__ __align__(16) u16 Vl[2][128 * 64];  // [d][k] swizzled (32KB)
  const int tid = threadIdx.x;                   // 0..255
  const int w = tid >> 6, lane = tid & 63;       // w: 0..3
  const int q = lane & 31, hi = lane >> 5;
  const int bh = blockIdx.y;
  const int b = bh >> 5, h = bh & 31;
  const int kvh = h >> 2;                        // GQA: H/KV = 4
  const int bx = blockIdx.x;                     // 0..7

  const int xq = (q & 7) << 4;
  int koff[8][2], voff[4][4];
#pragma unroll
  for (int ds = 0; ds < 8; ++ds) {
    int c = (ds * 32 + hi * 16) ^ xq;
    koff[ds][0] = q * 256 + c;
    koff[ds][1] = (32 + q) * 256 + c;
  }
#pragma unroll
  for (int ks = 0; ks < 4; ++ks) {
    int c = (ks * 32 + hi * 16) ^ xq;
#pragma unroll
    for (int dt = 0; dt < 4; ++dt)
      voff[ks][dt] = (dt * 32 + q) * 128 + c;
  }

  const char* Kbase = (const char*)(Kr + (size_t)(b * KVsz + kvh) * Ssz * Dsz);
  const char* Vbase = (const char*)(Vt + (size_t)(b * KVsz + kvh) * Dsz * Ssz);

  auto STAGE = [&](int bu, int kt2) {            // 256 threads: 4+4 GLDS each
    const char* Kb = Kbase + (size_t)kt2 * (64 * 256);
    const char* Vb = Vbase + (size_t)kt2 * 128;   // 64 cols * 2B
#pragma unroll
    for (int j = 0; j < 4; ++j) {
      int flat = j * 256 + tid;
      int row = flat >> 4, colb = ((flat & 15) * 16) ^ ((row & 7) << 4);
      GLDS(Kb + (size_t)row * 256 + colb, (char*)&Kl[bu][0] + flat * 16);
    }
#pragma unroll
    for (int j = 0; j < 4; ++j) {
      int flat = j * 256 + tid;
      int row = flat >> 3, colb = ((flat & 7) * 16) ^ ((row & 7) << 4);
      GLDS(Vb + (size_t)row * (Ssz * 2) + colb, (char*)&Vl[bu][0] + flat * 16);
    }
  };

#pragma unroll 1
  for (int pass = 0; pass < 2; ++pass) {
    const int bxr = pass ? bx : (15 - bx);       // q-tile index (128 rows)
    const int q0 = bxr * 128;
    const int qw = q0 + w * 32;
    const int ntiles = 2 * bxr + 2;              // always even
    const int qg = qw + q;

    const u16* Qb = Qr + ((size_t)bh * Ssz + qw + q) * Dsz + hi * 8;
    bf16x8 qf[8];
#pragma unroll
    for (int ds = 0; ds < 8; ++ds)
      qf[ds] = __builtin_bit_cast(bf16x8, *(const u16x8*)(Qb + ds * 16));

    f32x16 oacc[4];
#pragma unroll
    for (int dt = 0; dt < 4; ++dt)
#pragma unroll
      for (int r = 0; r < 16; ++r) oacc[dt][r] = 0.f;
    float mr = -1e30f, lr = 0.f;

    STAGE(0, 0);
    __syncthreads();

    auto TILE = [&](int bufc, int kt) {
      const int k0 = kt * 64;
      if (kt + 1 < ntiles) STAGE(bufc ^ 1, kt + 1);  // prefetch overlaps compute

      if (k0 <= qw + 31) {                           // wave participates
        const char* Kb = (const char*)&Kl[bufc][0];
        const char* Vb = (const char*)&Vl[bufc][0];
        f32x16 pa0, pa1;
#pragma unroll
        for (int r = 0; r < 16; ++r) { pa0[r] = 0.f; pa1[r] = 0.f; }
        __builtin_amdgcn_s_setprio(1);
#pragma unroll
        for (int ds = 0; ds < 8; ++ds) {
          bf16x8 kf0 = __builtin_bit_cast(bf16x8, *(const u16x8*)(Kb + koff[ds][0]));
          pa0 = __builtin_amdgcn_mfma_f32_32x32x16_bf16(kf0, qf[ds], pa0, 0, 0, 0);
          bf16x8 kf1 = __builtin_bit_cast(bf16x8, *(const u16x8*)(Kb + koff[ds][1]));
          pa1 = __builtin_amdgcn_mfma_f32_32x32x16_bf16(kf1, qf[ds], pa1, 0, 0, 0);
        }
        __builtin_amdgcn_s_setprio(0);

        if (k0 + 63 > qw) {                          // causal mask (tail tiles)
#pragma unroll
          for (int reg = 0; reg < 16; ++reg) {
            const int kb = (reg & 3) + 8 * (reg >> 2) + 4 * hi;
            if (k0 + kb > qg)      pa0[reg] = -1e30f;
            if (k0 + 32 + kb > qg) pa1[reg] = -1e30f;
          }
        }
        float tmx[16];
#pragma unroll
        for (int i = 0; i < 16; ++i) tmx[i] = fmaxf(pa0[i], pa1[i]);
#pragma unroll
        for (int s = 8; s > 0; s >>= 1)
#pragma unroll
          for (int i = 0; i < s; ++i) tmx[i] = fmaxf(tmx[i], tmx[i + s]);
        const float mx = fmaxf(tmx[0], __shfl_xor(tmx[0], 32, 64));
        if (!__all(mx <= mr + 8.0f)) {               // T13 defer-max (THR=8)
          const float mnew = fmaxf(mr, mx);
          const float corr = exp2f(mr - mnew);
          lr *= corr;
#pragma unroll
          for (int dt = 0; dt < 4; ++dt)
#pragma unroll
            for (int reg = 0; reg < 16; ++reg) oacc[dt][reg] *= corr;
          mr = mnew;
        }
        float su[16];
#pragma unroll
        for (int reg = 0; reg < 16; ++reg) {
          pa0[reg] = exp2f(pa0[reg] - mr);
          pa1[reg] = exp2f(pa1[reg] - mr);
          su[reg] = pa0[reg] + pa1[reg];
        }
#pragma unroll
        for (int s = 8; s > 0; s >>= 1)
#pragma unroll
          for (int i = 0; i < s; ++i) su[i] += su[i + s];
        lr += su[0] + __shfl_xor(su[0], 32, 64);

        uint32_t W0[4][2], W1[4][2];
#pragma unroll
        for (int r2 = 0; r2 < 4; ++r2)
#pragma unroll
          for (int c = 0; c < 2; ++c) {
            W0[r2][c] = packc(pa0[4 * r2 + 2 * c], pa0[4 * r2 + 2 * c + 1]);
            W1[r2][c] = packc(pa1[4 * r2 + 2 * c], pa1[4 * r2 + 2 * c + 1]);
          }

        __builtin_amdgcn_s_setprio(1);
#pragma unroll
        for (int ks = 0; ks < 4; ++ks) {
          const int T = ks >> 1, r2e = 2 * (ks & 1);
          uint32_t a0 = T ? W1[r2e][0]     : W0[r2e][0];
          uint32_t a1 = T ? W1[r2e][1]     : W0[r2e][1];
          uint32_t b0 = T ? W1[r2e + 1][0] : W0[r2e + 1][0];
          uint32_t b1 = T ? W1[r2e + 1][1] : W0[r2e + 1][1];
          asm("v_permlane32_swap_b32 %0, %1" : "+v"(a0), "+v"(b0));
          asm("v_permlane32_swap_b32 %0, %1" : "+v"(a1), "+v"(b1));
          u32x4 fw; fw[0] = a0; fw[1] = a1; fw[2] = b0; fw[3] = b1;
          bf16x8 pf = __builtin_bit_cast(bf16x8, fw);
#pragma unroll
          for (int dt = 0; dt < 4; ++dt) {
            bf16x8 vf = __builtin_bit_cast(bf16x8, *(const u16x8*)(Vb + voff[ks][dt]));
            oacc[dt] = __builtin_amdgcn_mfma_f32_32x32x16_bf16(vf, pf, oacc[dt], 0, 0, 0);
          }
        }
        __builtin_amdgcn_s_setprio(0);
      }
      __syncthreads();                               // drains vmcnt: next buf ready
    };

    for (int kt = 0; kt < ntiles; kt += 2) {         // ntiles % 2 == 0 always
      TILE(0, kt);
      TILE(1, kt + 1);
    }

    const float inv = 1.f / lr;
    u16* Ob = AO + ((size_t)(b * Ssz) + qw + q) * HIDsz + h * Dsz + hi * 4;
#pragma unroll
    for (int dt = 0; dt < 4; ++dt)
#pragma unroll
      for (int r2 = 0; r2 < 4; ++r2) {
        u16x4 o4;
#pragma unroll
        for (int j = 0; j < 4; ++j) o4[j] = f2bf(oacc[dt][4 * r2 + j] * inv);
        *(u16x4*)(Ob + dt * 32 + r2 * 8) = o4;
      }
  }
}

// ---------------- host ----------------
extern "C" void kernel_launch(void* const* d_in, const int* in_sizes, int n_in,
                              void* d_out, int out_size, void* d_ws, size_t ws_size,
                              hipStream_t stream) {
  (void)in_sizes; (void)n_in; (void)out_size;
  const float* hs   = (const float*)d_in[0];
  const int*   pos  = (const int*)d_in[1];
  const float* Wqkv = (const float*)d_in[2];
  const float* Wo   = (const float*)d_in[3];

  char* ws = (char*)d_ws;
  const size_t SZ_XBF = (size_t)4096 * 4096 * 2;   // also reused for AO
  const size_t SZ_WQ  = (size_t)6144 * 4096 * 2;
  const size_t SZ_WO  = (size_t)4096 * 4096 * 2;
  const size_t SZ_QR  = (size_t)Bsz * Hsz * Ssz * Dsz * 2;
  const size_t SZ_KR  = (size_t)Bsz * KVsz * Ssz * Dsz * 2;
  const size_t SZ_VT  = SZ_KR;

  size_t off = 0;
  u16*   Xbf   = (u16*)(ws + off);  off += SZ_XBF;
  u16*   Wq_bf = (u16*)(ws + off);  off += SZ_WQ;
  u16*   Wo_bf = (u16*)(ws + off);  off += SZ_WO;
  u16*   Qr    = (u16*)(ws + off);  off += SZ_QR;
  u16*   Kr    = (u16*)(ws + off);  off += SZ_KR;
  u16*   Vt    = (u16*)(ws + off);  off += SZ_VT;
  u16*   AO    = Xbf;                               // alias (Xbf dead after gemm1)
  float* Cp    = (float*)d_out;                     // K-split partials: d_out as
                                                    // scratch, fully overwritten
                                                    // by gemmO afterwards
  if (ws_size < off) return;                        // fail loudly

  // 1. fp32 -> bf16 conversions (single launch)
  k_cvt3<<<(N4_HS + N4_WQ + N4_WO + 255) / 256, 256, 0, stream>>>(
      hs, Wqkv, Wo, Xbf, Wq_bf, Wo_bf);

  // 2. QKV projection, merged Q + K/V-split (512 blocks, Q first) ->
  //    Qr (RoPE'd) + Cp partials
  k_gemmQKV<<<512, 512, 0, stream>>>(Xbf, Wq_bf, Cp, pos, Qr);

  // 3. merged fixup: sum partials + RoPE-K -> Kr ; sum + transpose -> Vt
  k_fixKV<<<8192 + 1024, 256, 0, stream>>>(Cp, pos, Kr, Vt);

  // 4. causal GQA attention (folded triangle, 2 blocks/CU TLP) -> AO
  k_attn<<<dim3(8, Bsz * Hsz), 256, 0, stream>>>(Qr, Kr, Vt, AO);

  // 5. o_proj -> d_out fp32 (overwrites scratch)
  k_gemmO<<<256, 512, 0, stream>>>(AO, Wo_bf, (float*)d_out);
}